// Round 3
// baseline (407.923 us; speedup 1.0000x reference)
//
#include <hip/hip_runtime.h>
#include <hip/hip_bf16.h>

#define BROWS 131072
#define HD 128
#define TPB 8   // tiles (of 64 rows) per persistent block

typedef __attribute__((ext_vector_type(8))) short bf16x8;
typedef __attribute__((ext_vector_type(4))) float f32x4;

static __device__ __forceinline__ unsigned short f2bf(float f) {
    union { float f; unsigned int i; } v;
    v.f = f;
    unsigned int u = v.i;
    u += 0x7FFFu + ((u >> 16) & 1u);
    return (unsigned short)(u >> 16);
}
static __device__ __forceinline__ float fast_sigmoid(float x) {
    float e = __builtin_amdgcn_exp2f(-1.442695040888963f * x);
    return __builtin_amdgcn_rcpf(1.0f + e);
}
static __device__ __forceinline__ float fast_tanh(float x) {
    float e = __builtin_amdgcn_exp2f(2.885390081777927f * x);
    return 1.0f - 2.0f * __builtin_amdgcn_rcpf(1.0f + e);
}

// Convert 8 f32 (held in regs) to a bf16x8 fragment (v_cvt_pk_bf16_f32).
static __device__ __forceinline__ bf16x8 cvt8r(f32x4 a, f32x4 b) {
    __hip_bfloat162 r0 = __float22bfloat162_rn(float2{a[0], a[1]});
    __hip_bfloat162 r1 = __float22bfloat162_rn(float2{a[2], a[3]});
    __hip_bfloat162 r2 = __float22bfloat162_rn(float2{b[0], b[1]});
    __hip_bfloat162 r3 = __float22bfloat162_rn(float2{b[2], b[3]});
    union { __hip_bfloat162 h2; unsigned int u; } u0, u1, u2, u3;
    u0.h2 = r0; u1.h2 = r1; u2.h2 = r2; u3.h2 = r3;
    union { unsigned int u[4]; bf16x8 v; } out;
    out.u[0] = u0.u; out.u[1] = u1.u; out.u[2] = u2.u; out.u[3] = u3.u;
    return out.v;
}

// Pack weights (f32, [k][n] row-major, 128x128 each) into bf16
// pack[(g*128 + n)*256 + k];  k<128 -> input-weight row k, k>=128 -> hidden
// weight row k-128. Slice s of gate g is the contiguous 8 KB region
// pack + ((g*8+s)*16)*256. Total 256 KB -> L2-resident.
__global__ void pack_weights(const float* __restrict__ w_ii,
                             const float* __restrict__ w_if,
                             const float* __restrict__ w_ig,
                             const float* __restrict__ w_io,
                             const float* __restrict__ w_hi,
                             const float* __restrict__ w_hf,
                             const float* __restrict__ w_hg,
                             const float* __restrict__ w_ho,
                             unsigned short* __restrict__ pack) {
    int idx = blockIdx.x * 256 + threadIdx.x;   // 0 .. 131071
    int n = idx & 127;
    int k = (idx >> 7) & 255;
    int g = idx >> 15;
    const float* wx = (g == 0) ? w_ii : (g == 1) ? w_if : (g == 2) ? w_ig : w_io;
    const float* wh = (g == 0) ? w_hi : (g == 1) ? w_hf : (g == 2) ? w_hg : w_ho;
    float v = (k < 128) ? wx[k * 128 + n] : wh[(k - 128) * 128 + n];
    pack[(g * 128 + n) * 256 + k] = f2bf(v);
}

// Persistent pipelined version.
// grid(256), 1024 threads (16 waves) -> exactly 1 block per CU; each block
// processes TPB=8 consecutive 64-row tiles with a double-buffered A-LDS
// (2 x 32 KB) software pipeline:
//   per tile t: issue A(t+1) global loads -> regs, issue c_prev(t) loads,
//   K-loop(t) from LDS buf[t&1] + L2-resident pack, epilogue(t),
//   cvt+ds_write A(t+1) -> buf[(t+1)&1], one barrier.
// All HBM latencies (stage, c_prev) hide under K-loop+epilogue of the
// current tile instead of being serially exposed per phase.
// Wave w: col-slice s = w&7 (16 cols x 4 gates), m-half mh = w>>3
// -> acc[2][4] = 32 AGPR; ~105 total regs < 128 cap of (1024,4), no spill.
__global__ __launch_bounds__(1024, 4)
void lstm_main(const float* __restrict__ x,
               const float* __restrict__ h_prev,
               const float* __restrict__ c_prev,
               const unsigned short* __restrict__ pack,
               const float* __restrict__ b_i,
               const float* __restrict__ b_f,
               const float* __restrict__ b_g,
               const float* __restrict__ b_o,
               float* __restrict__ out) {
    __shared__ bf16x8 alds8[2][2048];             // 2 x 32 KB

    const int tid  = threadIdx.x;
    const int wid  = tid >> 6;                    // 0..15
    const int lane = tid & 63;
    const int ml   = lane & 15;
    const int q    = lane >> 4;                   // 0..3
    const int s    = wid & 7;                     // 16-col slice
    const int mh   = wid >> 3;                    // m-half 0..1

    const int tile0 = blockIdx.x * TPB;

    // staging coords: chunk c = i*1024 + tid; row = c>>5 (0..63), kc = c&31
    // (8 k-elems each; kc<16 -> x, else h_prev). Swizzle kc by row&7.
    int srow[2], skc[2];
    #pragma unroll
    for (int i = 0; i < 2; ++i) {
        int c = i * 1024 + tid;
        srow[i] = c >> 5;
        skc[i]  = c & 31;
    }

    f32x4 sA[2][2];                               // staged A regs (32 B/chunk)

    auto load_stage = [&](int t) {
        size_t rowbase = (size_t)(tile0 + t) * 64;
        #pragma unroll
        for (int i = 0; i < 2; ++i) {
            const float* src = (skc[i] < 16)
                ? (x      + (rowbase + srow[i]) * 128 + skc[i] * 8)
                : (h_prev + (rowbase + srow[i]) * 128 + (skc[i] - 16) * 8);
            sA[i][0] = ((const f32x4*)src)[0];
            sA[i][1] = ((const f32x4*)src)[1];
        }
    };
    auto write_stage = [&](int buf) {
        #pragma unroll
        for (int i = 0; i < 2; ++i) {
            unsigned short* dst = (unsigned short*)alds8[buf]
                + srow[i] * 256 + (skc[i] ^ (srow[i] & 7)) * 8;
            *(bf16x8*)dst = cvt8r(sA[i][0], sA[i][1]);
        }
    };

    const unsigned short* pbase = pack + ((size_t)s * 16 + ml) * 256 + q * 8;
    const int col = s * 16 + ml;                  // 0..127
    const float bi = b_i[col], bf_ = b_f[col], bg = b_g[col], bo = b_o[col];

    float* out_h = out;
    float* out_c = out + (size_t)BROWS * HD;

    // ---- prologue: stage tile 0 ----
    load_stage(0);
    write_stage(0);
    __syncthreads();

    for (int t = 0; t < TPB; ++t) {
        const int cur = t & 1;

        // issue next tile's A loads early (latency hides under K + epilogue)
        if (t + 1 < TPB) load_stage(t + 1);

        // issue this tile's c_prev loads early
        const size_t row0 = (size_t)(tile0 + t) * 64;
        float cp[2][4];
        #pragma unroll
        for (int j = 0; j < 2; ++j)
            #pragma unroll
            for (int r = 0; r < 4; ++r)
                cp[j][r] = c_prev[(row0 + (mh * 2 + j) * 16 + q * 4 + r) * 128 + col];

        // ---- K loop: 8 steps of K=32 ----
        f32x4 acc[2][4];
        #pragma unroll
        for (int j = 0; j < 2; ++j)
            #pragma unroll
            for (int g = 0; g < 4; ++g)
                acc[j][g] = (f32x4){0.f, 0.f, 0.f, 0.f};

        unsigned short* alds = (unsigned short*)alds8[cur];
        #pragma unroll 2
        for (int ks = 0; ks < 8; ++ks) {
            bf16x8 a[2];
            #pragma unroll
            for (int j = 0; j < 2; ++j) {
                int rowl = (mh * 2 + j) * 16 + ml;
                int kcs  = (ks * 4 + q) ^ (ml & 7);
                a[j] = *(const bf16x8*)(&alds[rowl * 256 + kcs * 8]);
            }
            bf16x8 b[4];
            #pragma unroll
            for (int g = 0; g < 4; ++g)
                b[g] = *(const bf16x8*)(pbase + (size_t)g * 8 * 16 * 256 + ks * 32);

            #pragma unroll
            for (int j = 0; j < 2; ++j)
                #pragma unroll
                for (int g = 0; g < 4; ++g)
                    acc[j][g] = __builtin_amdgcn_mfma_f32_16x16x32_bf16(
                        a[j], b[g], acc[j][g], 0, 0, 0);
        }

        // ---- epilogue ----
        #pragma unroll
        for (int j = 0; j < 2; ++j) {
            #pragma unroll
            for (int r = 0; r < 4; ++r) {
                size_t row = row0 + (mh * 2 + j) * 16 + q * 4 + r;
                float ai = acc[j][0][r] + bi;
                float af = acc[j][1][r] + bf_;
                float ag = acc[j][2][r] + bg;
                float ao = acc[j][3][r] + bo;
                float ig = fast_sigmoid(ai);
                float fg = fast_sigmoid(af);
                float gg = fast_tanh(ag);
                float og = fast_sigmoid(ao);
                float cv = fg * cp[j][r] + ig * gg;
                float hv = og * fast_tanh(cv);
                out_h[row * 128 + col] = hv;
                out_c[row * 128 + col] = cv;
            }
        }

        // write next tile's A into the other buffer, then one barrier
        if (t + 1 < TPB) write_stage(cur ^ 1);
        __syncthreads();
    }
}

extern "C" void kernel_launch(void* const* d_in, const int* in_sizes, int n_in,
                              void* d_out, int out_size, void* d_ws, size_t ws_size,
                              hipStream_t stream) {
    const float* x  = (const float*)d_in[0];
    const float* h  = (const float*)d_in[1];
    const float* c  = (const float*)d_in[2];
    unsigned short* pack = (unsigned short*)d_ws;   // 256 KB

    pack_weights<<<512, 256, 0, stream>>>(
        (const float*)d_in[3], (const float*)d_in[4],
        (const float*)d_in[5], (const float*)d_in[6],
        (const float*)d_in[7], (const float*)d_in[8],
        (const float*)d_in[9], (const float*)d_in[10],
        pack);

    dim3 grid(BROWS / (64 * TPB));   // 256 blocks, 1 per CU
    lstm_main<<<grid, 1024, 0, stream>>>(
        x, h, c, pack,
        (const float*)d_in[11], (const float*)d_in[12],
        (const float*)d_in[13], (const float*)d_in[14],
        (float*)d_out);
}